// Round 1
// baseline (507.514 us; speedup 1.0000x reference)
//
#include <hip/hip_runtime.h>
#include <hip/hip_bf16.h>

typedef unsigned short ushort_t;
typedef unsigned int uint_t;

typedef __attribute__((ext_vector_type(8))) short short8;
typedef __attribute__((ext_vector_type(4))) float f32x4;

#define BATCH 512
#define DK    512
#define CTOT  100000
#define BN    64            // classes per block
#define THRESH_C (-0.8775825618903728f)   // cos(pi - 0.5)
#define MM_C     (0.2397127693021015f)    // sin(0.5)*0.5

// round-to-nearest-even fp32 -> bf16
static __device__ __forceinline__ ushort_t f2bf(float f) {
    union { float f; uint_t u; } v; v.f = f;
    return (ushort_t)((v.u + 0x7FFFu + ((v.u >> 16) & 1u)) >> 16);
}

// ---------------------------------------------------------------------------
// Prep: normalize x rows -> bf16; compute fp32-exact target[b] from cos_lb.
// grid = 512 blocks (one per batch row), 256 threads.
// ---------------------------------------------------------------------------
__global__ __launch_bounds__(256) void arc_prep(
    const float* __restrict__ x, const int* __restrict__ label,
    const float* __restrict__ w, float* __restrict__ target,
    ushort_t* __restrict__ exb)
{
    const int b = blockIdx.x;
    const int t = threadIdx.x;
    __shared__ float red[8];

    const float2 xv = ((const float2*)(x + (size_t)b * DK))[t];
    float ss = xv.x * xv.x + xv.y * xv.y;
    #pragma unroll
    for (int o = 32; o; o >>= 1) ss += __shfl_xor(ss, o);
    if ((t & 63) == 0) red[t >> 6] = ss;
    __syncthreads();
    const float ssx = red[0] + red[1] + red[2] + red[3];
    const float rnx = 1.0f / sqrtf(ssx);

    ushort2 e;
    e.x = f2bf(xv.x * rnx);
    e.y = f2bf(xv.y * rnx);
    ((ushort2*)(exb + (size_t)b * DK))[t] = e;

    const int lb = label[b];
    const float2 wv = ((const float2*)(w + (size_t)lb * DK))[t];
    float ssw = wv.x * wv.x + wv.y * wv.y;
    float dot = xv.x * wv.x + xv.y * wv.y;
    #pragma unroll
    for (int o = 32; o; o >>= 1) { ssw += __shfl_xor(ssw, o); dot += __shfl_xor(dot, o); }
    __syncthreads();                 // guard red[] reuse
    if ((t & 63) == 0) { red[t >> 6] = ssw; red[4 + (t >> 6)] = dot; }
    __syncthreads();
    if (t == 0) {
        const float sw = red[0] + red[1] + red[2] + red[3];
        const float dt = red[4] + red[5] + red[6] + red[7];
        float cl = dt * rnx / sqrtf(sw);
        cl = fminf(fmaxf(cl, -1.0f), 1.0f);
        const float tg = (cl > THRESH_C) ? cosf(acosf(cl) + 0.5f) : (cl - MM_C);
        target[b] = tg;
    }
}

// ---------------------------------------------------------------------------
// Main: full-batch (512) x 64-class tile per block; weight read once from HBM.
// 512 threads = 8 waves laid out 4(M) x 2(N); 16x16x32 bf16 MFMA.
// Weight norm folded into epilogue: cos = acc * rsqrt(sumsq(w_row)).
// ---------------------------------------------------------------------------
__global__ __launch_bounds__(512, 2) void arc_main(
    const ushort_t* __restrict__ exb, const float* __restrict__ w,
    const int* __restrict__ label, const float* __restrict__ target,
    float* __restrict__ out)
{
    // row stride 40 elems (80 B): 2-way LDS bank aliasing only (free)
    __shared__ ushort_t As[BATCH * 40];
    __shared__ ushort_t Bs[BN * 40];
    __shared__ float rnw[BN];
    __shared__ float tgt_s[BATCH];
    __shared__ int   lbl_s[BATCH];

    const int t    = threadIdx.x;
    const int lane = t & 63;
    const int wid  = t >> 6;
    const int wm   = wid >> 1;       // 0..3  (M partition, 128 rows each)
    const int wn   = wid & 1;        // 0..1  (N partition, 32 cols each)
    const int c0   = blockIdx.x * BN;

    tgt_s[t] = target[t];
    lbl_s[t] = label[t];

    f32x4 acc[8][2];
    #pragma unroll
    for (int i = 0; i < 8; ++i)
        #pragma unroll
        for (int j = 0; j < 2; ++j)
            acc[i][j] = (f32x4){0.f, 0.f, 0.f, 0.f};

    // B staging assignment: 8 threads per class row
    const int bclsl  = t >> 3;                    // 0..63 local class
    const int bcls   = c0 + bclsl;
    const int bcol0  = (t & 7) * 4;               // col within 32-chunk
    const bool bvalid = (bcls < CTOT);
    const float* wrow = w + (size_t)bcls * DK;
    float bsq = 0.0f;

    const ushort_t* arow = exb + (size_t)t * DK;  // thread t stages batch row t
    const int ak = (lane >> 4) * 8;               // frag k-offset in chunk

    for (int ko = 0; ko < 16; ++ko) {
        __syncthreads();
        // ---- stage A chunk: 512 x 32 bf16
        {
            const uint4* ap = (const uint4*)(arow + ko * 32);
            uint4 a0 = ap[0], a1 = ap[1], a2 = ap[2], a3 = ap[3];
            uint4* ad = (uint4*)&As[t * 40];
            ad[0] = a0; ad[1] = a1; ad[2] = a2; ad[3] = a3;
        }
        // ---- stage B chunk: 64 x 32 (fp32 -> bf16), accumulate sumsq (fp32)
        {
            float4 bq = bvalid ? *(const float4*)(wrow + ko * 32 + bcol0)
                               : make_float4(0.f, 0.f, 0.f, 0.f);
            bsq += bq.x * bq.x + bq.y * bq.y + bq.z * bq.z + bq.w * bq.w;
            uint2 bp;
            bp.x = (uint_t)f2bf(bq.x) | ((uint_t)f2bf(bq.y) << 16);
            bp.y = (uint_t)f2bf(bq.z) | ((uint_t)f2bf(bq.w) << 16);
            *(uint2*)&Bs[bclsl * 40 + bcol0] = bp;
        }
        __syncthreads();

        // ---- MFMA: 8 m-tiles x 2 n-tiles per wave
        short8 bfr[2];
        #pragma unroll
        for (int nt = 0; nt < 2; ++nt) {
            const int cl = wn * 32 + nt * 16 + (lane & 15);
            bfr[nt] = *(const short8*)&Bs[cl * 40 + ak];
        }
        #pragma unroll
        for (int mt = 0; mt < 8; ++mt) {
            const int r = wm * 128 + mt * 16 + (lane & 15);
            const short8 afr = *(const short8*)&As[r * 40 + ak];
            acc[mt][0] = __builtin_amdgcn_mfma_f32_16x16x32_bf16(afr, bfr[0], acc[mt][0], 0, 0, 0);
            acc[mt][1] = __builtin_amdgcn_mfma_f32_16x16x32_bf16(afr, bfr[1], acc[mt][1], 0, 0, 0);
        }
    }

    // per-class inverse norm (8-lane reduce, groups lie inside one wave)
    bsq += __shfl_xor(bsq, 1);
    bsq += __shfl_xor(bsq, 2);
    bsq += __shfl_xor(bsq, 4);
    if ((t & 7) == 0) rnw[bclsl] = 1.0f / sqrtf(bsq);
    __syncthreads();

    // ---- epilogue
    const int colbase = (lane & 15);
    const int rquad   = (lane >> 4) * 4;
    #pragma unroll
    for (int nt = 0; nt < 2; ++nt) {
        const int cll = wn * 32 + nt * 16 + colbase;   // local class
        const int cc  = c0 + cll;                      // global class
        if (cc >= CTOT) continue;
        const float rn  = rnw[cll];
        #pragma unroll
        for (int mt = 0; mt < 8; ++mt) {
            #pragma unroll
            for (int r = 0; r < 4; ++r) {
                const int brow = wm * 128 + mt * 16 + rquad + r;
                const float cosv = acc[mt][nt][r] * rn;
                const float tg = tgt_s[brow];
                const float d  = cosv - tg;
                const float ts = 1.2f * __expf(d * d * -0.5f);
                const float v  = (cc == lbl_s[brow]) ? 64.0f * tg
                                                     : 64.0f * (ts * cosv + ts - 1.0f);
                out[(size_t)brow * CTOT + cc] = v;
            }
        }
    }
}

extern "C" void kernel_launch(void* const* d_in, const int* in_sizes, int n_in,
                              void* d_out, int out_size, void* d_ws, size_t ws_size,
                              hipStream_t stream) {
    const float* x     = (const float*)d_in[0];
    const int*   label = (const int*)d_in[1];
    const float* w     = (const float*)d_in[2];
    float* out = (float*)d_out;

    float*    target = (float*)d_ws;                        // 512 fp32
    ushort_t* exb    = (ushort_t*)((char*)d_ws + 2048);     // 512x512 bf16

    arc_prep<<<512, 256, 0, stream>>>(x, label, w, target, exb);

    const int nblk = (CTOT + BN - 1) / BN;                  // 1563
    arc_main<<<nblk, 512, 0, stream>>>(exb, w, label, target, out);
}

// Round 2
// 468.174 us; speedup vs baseline: 1.0840x; 1.0840x over previous
//
#include <hip/hip_runtime.h>
#include <hip/hip_bf16.h>

typedef unsigned short ushort_t;
typedef unsigned int uint_t;

typedef __attribute__((ext_vector_type(8))) short short8;
typedef __attribute__((ext_vector_type(4))) float f32x4;

#define BATCH 512
#define DK    512
#define CTOT  100000
#define BN    64
#define THRESH_C (-0.8775825618903728f)   // cos(pi - 0.5)
#define MM_C     (0.2397127693021015f)    // sin(0.5)*0.5

// round-to-nearest-even fp32 -> bf16
static __device__ __forceinline__ ushort_t f2bf(float f) {
    union { float f; uint_t u; } v; v.f = f;
    return (ushort_t)((v.u + 0x7FFFu + ((v.u >> 16) & 1u)) >> 16);
}

// ---------------------------------------------------------------------------
// Prep: normalize x rows -> bf16; compute fp32-exact target[b] from cos_lb.
// grid = 512 blocks (one per batch row), 256 threads.
// ---------------------------------------------------------------------------
__global__ __launch_bounds__(256) void arc_prep(
    const float* __restrict__ x, const int* __restrict__ label,
    const float* __restrict__ w, float* __restrict__ target,
    ushort_t* __restrict__ exb)
{
    const int b = blockIdx.x;
    const int t = threadIdx.x;
    __shared__ float red[8];

    const float2 xv = ((const float2*)(x + (size_t)b * DK))[t];
    float ss = xv.x * xv.x + xv.y * xv.y;
    #pragma unroll
    for (int o = 32; o; o >>= 1) ss += __shfl_xor(ss, o);
    if ((t & 63) == 0) red[t >> 6] = ss;
    __syncthreads();
    const float ssx = red[0] + red[1] + red[2] + red[3];
    const float rnx = 1.0f / sqrtf(ssx);

    ushort2 e;
    e.x = f2bf(xv.x * rnx);
    e.y = f2bf(xv.y * rnx);
    ((ushort2*)(exb + (size_t)b * DK))[t] = e;

    const int lb = label[b];
    const float2 wv = ((const float2*)(w + (size_t)lb * DK))[t];
    float ssw = wv.x * wv.x + wv.y * wv.y;
    float dot = xv.x * wv.x + xv.y * wv.y;
    #pragma unroll
    for (int o = 32; o; o >>= 1) { ssw += __shfl_xor(ssw, o); dot += __shfl_xor(dot, o); }
    __syncthreads();                 // guard red[] reuse
    if ((t & 63) == 0) { red[t >> 6] = ssw; red[4 + (t >> 6)] = dot; }
    __syncthreads();
    if (t == 0) {
        const float sw = red[0] + red[1] + red[2] + red[3];
        const float dt = red[4] + red[5] + red[6] + red[7];
        float cl = dt * rnx / sqrtf(sw);
        cl = fminf(fmaxf(cl, -1.0f), 1.0f);
        const float tg = (cl > THRESH_C) ? cosf(acosf(cl) + 0.5f) : (cl - MM_C);
        target[b] = tg;
    }
}

// ---------------------------------------------------------------------------
// Main: per block, stage 64-class B-tile (full K) into LDS ONCE (64 KB,
// XOR-swizzled 16B chunks), then a barrier-free K-loop: A-frags straight
// from global exb (L2-hot), B-frags from LDS, 16x16x32 bf16 MFMA.
// 512 threads = 8 waves; wave w owns batch rows w*64..w*64+63, all 64 cols.
// Weight norm folded into epilogue: cos = acc * rsqrt(sumsq(w_row)).
// ---------------------------------------------------------------------------
__global__ __launch_bounds__(512, 4) void arc_main(
    const ushort_t* __restrict__ exb, const float* __restrict__ w,
    const int* __restrict__ label, const float* __restrict__ target,
    float* __restrict__ out)
{
    __shared__ ushort_t Bs[BN * DK];   // exactly 64 KB

    const int t    = threadIdx.x;
    const int lane = t & 63;
    const int wid  = t >> 6;
    const int c0   = blockIdx.x * BN;

    // ---- stage B tile: 8 threads per class row; fp32 -> bf16 + sumsq
    const int br  = t >> 3;            // 0..63 local class row
    const int bj  = t & 7;
    const int cls = c0 + br;
    const bool valid = (cls < CTOT);
    const float* wrow = w + (size_t)cls * DK;
    const int s3 = br & 7;             // xor-swizzle key for this row
    float bsq = 0.0f;
    #pragma unroll
    for (int i = 0; i < 16; ++i) {
        const int c = i * 32 + bj * 4;
        float4 q = valid ? *(const float4*)(wrow + c)
                         : make_float4(0.f, 0.f, 0.f, 0.f);
        bsq += q.x * q.x + q.y * q.y + q.z * q.z + q.w * q.w;
        uint2 p;
        p.x = (uint_t)f2bf(q.x) | ((uint_t)f2bf(q.y) << 16);
        p.y = (uint_t)f2bf(q.z) | ((uint_t)f2bf(q.w) << 16);
        const int k16 = c >> 3;                     // 16B-chunk index in row
        const int sw  = k16 ^ s3;
        *(uint2*)&Bs[br * DK + sw * 8 + (bj & 1) * 4] = p;
    }
    // 8-lane reduce (threads of one row are adjacent lanes)
    bsq += __shfl_xor(bsq, 1);
    bsq += __shfl_xor(bsq, 2);
    bsq += __shfl_xor(bsq, 4);
    __syncthreads();                   // B tile visible to all waves

    // ---- barrier-free K loop
    const int m0   = wid * 64;
    const int colq = lane & 15;
    const int qk   = lane >> 4;        // 0..3 k-subchunk
    const int bs3  = colq & 7;         // B swizzle key (nt*16 doesn't touch low3)
    const ushort_t* arow0 = exb + (size_t)(m0 + colq) * DK + qk * 8;

    f32x4 acc[4][4];
    #pragma unroll
    for (int i = 0; i < 4; ++i)
        #pragma unroll
        for (int j = 0; j < 4; ++j)
            acc[i][j] = (f32x4){0.f, 0.f, 0.f, 0.f};

    #pragma unroll 2
    for (int ko = 0; ko < 16; ++ko) {
        short8 bfr[4];
        #pragma unroll
        for (int nt = 0; nt < 4; ++nt) {
            const int idx = (nt * 16 + colq) * DK + (((ko << 2) | qk) ^ bs3) * 8;
            bfr[nt] = *(const short8*)&Bs[idx];
        }
        #pragma unroll
        for (int mt = 0; mt < 4; ++mt) {
            const short8 afr = *(const short8*)(arow0 + mt * 16 * DK + ko * 32);
            #pragma unroll
            for (int nt = 0; nt < 4; ++nt)
                acc[mt][nt] = __builtin_amdgcn_mfma_f32_16x16x32_bf16(afr, bfr[nt], acc[mt][nt], 0, 0, 0);
        }
    }

    // ---- exchange per-class inverse norms through Bs (B data now dead)
    __syncthreads();
    if ((t & 7) == 0) ((float*)Bs)[br] = valid ? (1.0f / sqrtf(bsq)) : 0.0f;
    __syncthreads();
    float rn[4];
    #pragma unroll
    for (int nt = 0; nt < 4; ++nt) rn[nt] = ((float*)Bs)[nt * 16 + colq];

    // ---- epilogue
    #pragma unroll
    for (int mt = 0; mt < 4; ++mt) {
        #pragma unroll
        for (int rr = 0; rr < 4; ++rr) {
            const int row = m0 + mt * 16 + qk * 4 + rr;
            const float tg = target[row];
            const int   lb = label[row];
            float* orow = out + (size_t)row * CTOT + c0;
            #pragma unroll
            for (int nt = 0; nt < 4; ++nt) {
                const int cc = c0 + nt * 16 + colq;
                if (cc >= CTOT) continue;
                const float cosv = acc[mt][nt][rr] * rn[nt];
                const float d  = cosv - tg;
                const float ts = 1.2f * __expf(d * d * -0.5f);
                const float v  = (cc == lb) ? 64.0f * tg
                                            : 64.0f * (ts * cosv + ts - 1.0f);
                orow[nt * 16 + colq] = v;
            }
        }
    }
}

extern "C" void kernel_launch(void* const* d_in, const int* in_sizes, int n_in,
                              void* d_out, int out_size, void* d_ws, size_t ws_size,
                              hipStream_t stream) {
    const float* x     = (const float*)d_in[0];
    const int*   label = (const int*)d_in[1];
    const float* w     = (const float*)d_in[2];
    float* out = (float*)d_out;

    float*    target = (float*)d_ws;                        // 512 fp32
    ushort_t* exb    = (ushort_t*)((char*)d_ws + 2048);     // 512x512 bf16

    arc_prep<<<512, 256, 0, stream>>>(x, label, w, target, exb);

    const int nblk = (CTOT + BN - 1) / BN;                  // 1563
    arc_main<<<nblk, 512, 0, stream>>>(exb, w, label, target, out);
}

// Round 3
// 413.998 us; speedup vs baseline: 1.2259x; 1.1309x over previous
//
#include <hip/hip_runtime.h>
#include <hip/hip_bf16.h>

typedef unsigned short ushort_t;
typedef unsigned int uint_t;

typedef __attribute__((ext_vector_type(8))) short short8;
typedef __attribute__((ext_vector_type(4))) float f32x4;

#define BATCH 512
#define DK    512
#define CTOT  100000
#define BN    64
#define THRESH_C (-0.8775825618903728f)   // cos(pi - 0.5)
#define MM_C     (0.2397127693021015f)    // sin(0.5)*0.5

// round-to-nearest-even fp32 -> bf16
static __device__ __forceinline__ ushort_t f2bf(float f) {
    union { float f; uint_t u; } v; v.f = f;
    return (ushort_t)((v.u + 0x7FFFu + ((v.u >> 16) & 1u)) >> 16);
}

// ---------------------------------------------------------------------------
// Prep: normalize x rows -> bf16 stored in MFMA-A-fragment-major order:
//   exbF[row_block(32)][ko(16)][lane(64)*8 elems]
//   element (b,k): row_block=b>>4, ko=k>>5, lane=(k>>3&3)*16+(b&15), j=k&7
// so the K-loop A-load (lane l reads 16B at base + l*16) is fully coalesced.
// Also computes fp32-exact target[b] from cos_lb.
// grid = 512 blocks (one per batch row), 256 threads.
// ---------------------------------------------------------------------------
__global__ __launch_bounds__(256) void arc_prep(
    const float* __restrict__ x, const int* __restrict__ label,
    const float* __restrict__ w, float* __restrict__ target,
    ushort_t* __restrict__ exbF)
{
    const int b = blockIdx.x;
    const int t = threadIdx.x;
    __shared__ float red[8];

    const float2 xv = ((const float2*)(x + (size_t)b * DK))[t];
    float ss = xv.x * xv.x + xv.y * xv.y;
    #pragma unroll
    for (int o = 32; o; o >>= 1) ss += __shfl_xor(ss, o);
    if ((t & 63) == 0) red[t >> 6] = ss;
    __syncthreads();
    const float ssx = red[0] + red[1] + red[2] + red[3];
    const float rnx = 1.0f / sqrtf(ssx);

    // write bf16 pair (k=2t, 2t+1) into fragment-major layout
    {
        const int k = 2 * t;
        const int ko = k >> 5;
        const int qk = (k >> 3) & 3;
        const int kj = k & 7;                       // even
        const size_t F = (size_t)(b >> 4) * 8192 + (size_t)ko * 512
                       + (size_t)qk * 128 + (size_t)(b & 15) * 8 + kj;
        ushort2 e;
        e.x = f2bf(xv.x * rnx);
        e.y = f2bf(xv.y * rnx);
        *(ushort2*)(exbF + F) = e;
    }

    const int lb = label[b];
    const float2 wv = ((const float2*)(w + (size_t)lb * DK))[t];
    float ssw = wv.x * wv.x + wv.y * wv.y;
    float dot = xv.x * wv.x + xv.y * wv.y;
    #pragma unroll
    for (int o = 32; o; o >>= 1) { ssw += __shfl_xor(ssw, o); dot += __shfl_xor(dot, o); }
    __syncthreads();                 // guard red[] reuse
    if ((t & 63) == 0) { red[t >> 6] = ssw; red[4 + (t >> 6)] = dot; }
    __syncthreads();
    if (t == 0) {
        const float sw = red[0] + red[1] + red[2] + red[3];
        const float dt = red[4] + red[5] + red[6] + red[7];
        float cl = dt * rnx / sqrtf(sw);
        cl = fminf(fmaxf(cl, -1.0f), 1.0f);
        const float tg = (cl > THRESH_C) ? cosf(acosf(cl) + 0.5f) : (cl - MM_C);
        target[b] = tg;
    }
}

// ---------------------------------------------------------------------------
// Main: per block, stage 64-class B-tile (full K) into LDS ONCE (64 KB,
// XOR-swizzled 16B chunks), then a barrier-free K-loop: A-frags from global
// exbF (fragment-major -> fully coalesced 1KB/instr, L2-hot), B-frags from
// LDS, 16x16x32 bf16 MFMA. 512 threads = 8 waves; wave w owns batch rows
// w*64..w*64+63, all 64 cols. cos = acc * rsqrt(sumsq(w_row)) in epilogue.
// ---------------------------------------------------------------------------
__global__ __launch_bounds__(512, 4) void arc_main(
    const ushort_t* __restrict__ exbF, const float* __restrict__ w,
    const int* __restrict__ label, const float* __restrict__ target,
    float* __restrict__ out)
{
    __shared__ ushort_t Bs[BN * DK];   // exactly 64 KB

    const int t    = threadIdx.x;
    const int lane = t & 63;
    const int wid  = t >> 6;
    const int c0   = blockIdx.x * BN;

    // ---- stage B tile: 8 threads per class row; fp32 -> bf16 + sumsq
    const int br  = t >> 3;            // 0..63 local class row
    const int bj  = t & 7;
    const int cls = c0 + br;
    const bool valid = (cls < CTOT);
    const float* wrow = w + (size_t)cls * DK;
    const int s3 = br & 7;             // xor-swizzle key for this row
    float bsq = 0.0f;
    #pragma unroll
    for (int i = 0; i < 16; ++i) {
        const int c = i * 32 + bj * 4;
        float4 q = valid ? *(const float4*)(wrow + c)
                         : make_float4(0.f, 0.f, 0.f, 0.f);
        bsq += q.x * q.x + q.y * q.y + q.z * q.z + q.w * q.w;
        uint2 p;
        p.x = (uint_t)f2bf(q.x) | ((uint_t)f2bf(q.y) << 16);
        p.y = (uint_t)f2bf(q.z) | ((uint_t)f2bf(q.w) << 16);
        const int k16 = c >> 3;                     // 16B-chunk index in row
        const int sw  = k16 ^ s3;
        *(uint2*)&Bs[br * DK + sw * 8 + (bj & 1) * 4] = p;
    }
    // 8-lane reduce (threads of one row are adjacent lanes)
    bsq += __shfl_xor(bsq, 1);
    bsq += __shfl_xor(bsq, 2);
    bsq += __shfl_xor(bsq, 4);
    __syncthreads();                   // B tile visible to all waves

    // ---- barrier-free K loop; A-loads fully coalesced from fragment layout
    const int m0   = wid * 64;
    const int colq = lane & 15;
    const int qk   = lane >> 4;        // 0..3 k-subchunk
    const int bs3  = colq & 7;         // B swizzle key (nt*16 doesn't touch low3)
    // wave's A base: row_block = wid*4 (+mt), stride 8192 per row_block, 512 per ko
    const ushort_t* abase = exbF + (size_t)(wid * 4) * 8192 + (size_t)lane * 8;

    f32x4 acc[4][4];
    #pragma unroll
    for (int i = 0; i < 4; ++i)
        #pragma unroll
        for (int j = 0; j < 4; ++j)
            acc[i][j] = (f32x4){0.f, 0.f, 0.f, 0.f};

    #pragma unroll 2
    for (int ko = 0; ko < 16; ++ko) {
        short8 bfr[4];
        #pragma unroll
        for (int nt = 0; nt < 4; ++nt) {
            const int idx = (nt * 16 + colq) * DK + (((ko << 2) | qk) ^ bs3) * 8;
            bfr[nt] = *(const short8*)&Bs[idx];
        }
        #pragma unroll
        for (int mt = 0; mt < 4; ++mt) {
            const short8 afr = *(const short8*)(abase + (size_t)mt * 8192 + ko * 512);
            #pragma unroll
            for (int nt = 0; nt < 4; ++nt)
                acc[mt][nt] = __builtin_amdgcn_mfma_f32_16x16x32_bf16(afr, bfr[nt], acc[mt][nt], 0, 0, 0);
        }
    }

    // ---- exchange per-class inverse norms through Bs (B data now dead)
    __syncthreads();
    if ((t & 7) == 0) ((float*)Bs)[br] = valid ? (1.0f / sqrtf(bsq)) : 0.0f;
    __syncthreads();
    float rn[4];
    #pragma unroll
    for (int nt = 0; nt < 4; ++nt) rn[nt] = ((float*)Bs)[nt * 16 + colq];

    // ---- epilogue
    #pragma unroll
    for (int mt = 0; mt < 4; ++mt) {
        #pragma unroll
        for (int rr = 0; rr < 4; ++rr) {
            const int row = m0 + mt * 16 + qk * 4 + rr;
            const float tg = target[row];
            const int   lb = label[row];
            float* orow = out + (size_t)row * CTOT + c0;
            #pragma unroll
            for (int nt = 0; nt < 4; ++nt) {
                const int cc = c0 + nt * 16 + colq;
                if (cc >= CTOT) continue;
                const float cosv = acc[mt][nt][rr] * rn[nt];
                const float d  = cosv - tg;
                const float ts = 1.2f * __expf(d * d * -0.5f);
                const float v  = (cc == lb) ? 64.0f * tg
                                            : 64.0f * (ts * cosv + ts - 1.0f);
                orow[nt * 16 + colq] = v;
            }
        }
    }
}

extern "C" void kernel_launch(void* const* d_in, const int* in_sizes, int n_in,
                              void* d_out, int out_size, void* d_ws, size_t ws_size,
                              hipStream_t stream) {
    const float* x     = (const float*)d_in[0];
    const int*   label = (const int*)d_in[1];
    const float* w     = (const float*)d_in[2];
    float* out = (float*)d_out;

    float*    target = (float*)d_ws;                        // 512 fp32
    ushort_t* exbF   = (ushort_t*)((char*)d_ws + 2048);     // 512x512 bf16, frag-major

    arc_prep<<<512, 256, 0, stream>>>(x, label, w, target, exbF);

    const int nblk = (CTOT + BN - 1) / BN;                  // 1563
    arc_main<<<nblk, 512, 0, stream>>>(exbF, w, label, target, out);
}